// Round 2
// baseline (717.461 us; speedup 1.0000x reference)
//
#include <hip/hip_runtime.h>

// NNOpenSetClassifier — R4: global_load_lds + 4-buffer counted-vmcnt pipeline.
//   frame [8,16384,128] f32, templates [64,16384,128] f32, classes [64] int
// Outputs (concat f32): masked_pred [8,N,21], mask [8,N], ncm [8,N],
//                       min_d [8,N], neigh_classes [8,N]
//
// Block owns P=16 pixels, loops t=0..63 templates.
//  - template tile (8KB contiguous) staged via __builtin_amdgcn_global_load_lds
//    (width 16): no VGPR round-trip, no ds_write, no mid-loop vmcnt(0).
//  - 4 LDS buffers, 3 tiles in flight, s_waitcnt vmcnt(4) per iter (counted,
//    never 0 in steady state) -> HBM latency spans 2+ iterations of compute.
//  - gload_lds writes lane-linear, so bank-conflict fix is a both-sides XOR
//    swizzle (chunk ^= (chunk>>5)&7): inverse-swizzled GLOBAL source address
//    (permutes 16B chunks within 128B segments -> still coalesced) + same XOR
//    on the ds_read offset. For fixed kq the 64 lanes cover all 8 bank quads.
//  - frame rows in registers (64 VGPR), read from HBM once, oldest vmem ops.

#define NPIX   16384
#define DDIM   128
#define NT     64
#define NB     8
#define NCAT   21
#define THRESH 230.0f
#define P      16

typedef float4 f4;

__device__ __forceinline__ void dma16(const float* g, float* l) {
    __builtin_amdgcn_global_load_lds(
        (const __attribute__((address_space(1))) void*)g,
        (__attribute__((address_space(3))) void*)l,
        16 /*bytes, literal*/, 0, 0);
}

__global__ __launch_bounds__(256, 4) void nn_openset_kernel(
    const float* __restrict__ frame,   // [8, 16384, 128]
    const float* __restrict__ tmpl,    // [64, 16384, 128]
    const int*   __restrict__ tcls,    // [64]
    float* __restrict__ out)
{
    __shared__ __align__(16) float ts[4][P * DDIM];   // 4 x 8192 B, linear layout

    const int tid = threadIdx.x;
    const int n0  = blockIdx.x * P;

    // thread = (batch-pair bp, pixel np, d-quarter dq)
    const int bp = tid >> 6;
    const int ln = tid & 63;
    const int np = ln >> 2;           // 0..15
    const int dq = ln & 3;            // 0..3
    const int b0 = bp * 2, b1 = b0 + 1;
    const int n  = n0 + np;
    const int wv = __builtin_amdgcn_readfirstlane(bp);

    // ---- frame quarter-rows into registers FIRST (oldest vmem ops) ----
    f4 fr0[8], fr1[8];
    {
        const f4* f0 = (const f4*)(frame + ((size_t)b0 * NPIX + n) * DDIM + dq * 32);
        const f4* f1 = (const f4*)(frame + ((size_t)b1 * NPIX + n) * DDIM + dq * 32);
        #pragma unroll
        for (int j = 0; j < 8; ++j) { fr0[j] = f0[j]; fr1[j] = f1[j]; }
    }

    // ---- template DMA setup: this thread stages 16B chunks c0, c1 ----
    const size_t PLANE = (size_t)NPIX * DDIM;        // floats per template plane
    const int c0  = tid;                             // chunks 0..255
    const int c1  = tid + 256;                       // chunks 256..511
    const int sc0 = c0 ^ ((c0 >> 5) & 7);            // inverse-swizzled src chunk
    const int sc1 = c1 ^ ((c1 >> 5) & 7);
    const float* gp0 = tmpl + (size_t)n0 * DDIM + sc0 * 4;
    const float* gp1 = tmpl + (size_t)n0 * DDIM + sc1 * 4;
    const int ldso0 = wv * 256;                      // wave-uniform LDS float base
    const int ldso1 = 1024 + wv * 256;

    // prologue: issue tiles 0,1,2 (3 in flight)
    dma16(gp0,             &ts[0][ldso0]);  dma16(gp1,             &ts[0][ldso1]);
    dma16(gp0 + PLANE,     &ts[1][ldso0]);  dma16(gp1 + PLANE,     &ts[1][ldso1]);
    dma16(gp0 + 2 * PLANE, &ts[2][ldso0]);  dma16(gp1 + 2 * PLANE, &ts[2][ldso1]);
    gp0 += 3 * PLANE;  gp1 += 3 * PLANE;

    // loop-invariant swizzled read offsets (floats)
    const int s  = np & 7;
    const int rb = np * DDIM + dq * 32;
    int roff[8];
    #pragma unroll
    for (int kq = 0; kq < 8; ++kq) roff[kq] = rb + ((kq ^ s) << 2);

    // drains frame loads + tile 0 (16 fr + 2 dma retire), leaves tiles 1,2 in flight
    asm volatile("s_waitcnt vmcnt(4)" ::: "memory");
    __builtin_amdgcn_s_barrier();

    float vmin0 = 3.402823466e38f, vmin1 = 3.402823466e38f;
    int   imin0 = 0, imin1 = 0;

    for (int t = 0; t < NT; ++t) {
        // issue tile t+3 into buf[(t+3)&3] (its last readers finished at iter t-1,
        // which every wave has passed thanks to the end-of-iter barrier)
        if (t + 3 < NT) {
            float* wb = ts[(t + 3) & 3];
            dma16(gp0, wb + ldso0);
            dma16(gp1, wb + ldso1);
            gp0 += PLANE;  gp1 += PLANE;
        }

        // compute tile t (readiness guaranteed by previous iter's vmcnt+barrier)
        const float* tb = ts[t & 3];
        float a0 = 0.0f, a1 = 0.0f;
        #pragma unroll
        for (int kq = 0; kq < 8; ++kq) {
            const f4 tv = *(const f4*)(tb + roff[kq]);   // ds_read_b128, swizzled
            const f4 x0 = fr0[kq];
            const f4 x1 = fr1[kq];
            float d;
            d = x0.x - tv.x; a0 = fmaf(d, d, a0);
            d = x0.y - tv.y; a0 = fmaf(d, d, a0);
            d = x0.z - tv.z; a0 = fmaf(d, d, a0);
            d = x0.w - tv.w; a0 = fmaf(d, d, a0);
            d = x1.x - tv.x; a1 = fmaf(d, d, a1);
            d = x1.y - tv.y; a1 = fmaf(d, d, a1);
            d = x1.z - tv.z; a1 = fmaf(d, d, a1);
            d = x1.w - tv.w; a1 = fmaf(d, d, a1);
        }
        // combine the 4 d-quarters (lanes np*4+dq)
        a0 += __shfl_xor(a0, 1);  a0 += __shfl_xor(a0, 2);
        a1 += __shfl_xor(a1, 1);  a1 += __shfl_xor(a1, 2);

        // running min/argmin (ascending t, strict '<' => lowest index on ties)
        const bool u0 = a0 < vmin0;
        const bool u1 = a1 < vmin1;
        imin0 = u0 ? t : imin0;  vmin0 = u0 ? a0 : vmin0;
        imin1 = u1 ? t : imin1;  vmin1 = u1 ? a1 : vmin1;

        // counted wait: tile t+1 must be resident; keep the rest in flight
        if (t < NT - 1) {
            if (t < NT - 3)       asm volatile("s_waitcnt vmcnt(4)" ::: "memory");
            else if (t == NT - 3) asm volatile("s_waitcnt vmcnt(2)" ::: "memory");
            else                  asm volatile("s_waitcnt vmcnt(0)" ::: "memory");
            __builtin_amdgcn_s_barrier();
        }
    }

    // ---- epilogue: all 4 dq lanes hold identical (vmin, imin); split writes ----
    const int  cls0 = tcls[imin0];
    const int  cls1 = tcls[imin1];
    const bool m0 = (vmin0 <= THRESH);
    const bool m1 = (vmin1 <= THRESH);

    float* o0 = out;                                  // masked_pred [8,N,21]
    float* o1 = out + (size_t)NB * NPIX * NCAT;       // mask        [8,N]
    float* o2 = o1 + NB * NPIX;                       // ncm         [8,N]
    float* o3 = o2 + NB * NPIX;                       // min_d       [8,N]
    float* o4 = o3 + NB * NPIX;                       // neigh_cls   [8,N]

    const size_t p0 = (size_t)b0 * NPIX + n;
    const size_t p1 = (size_t)b1 * NPIX + n;

    if (dq == 0)      { o1[p0] = m0 ? 1.0f : 0.0f;          o1[p1] = m1 ? 1.0f : 0.0f; }
    else if (dq == 1) { o2[p0] = m0 ? (float)cls0 : 20.0f;  o2[p1] = m1 ? (float)cls1 : 20.0f; }
    else if (dq == 2) { o3[p0] = vmin0;                     o3[p1] = vmin1; }
    else              { o4[p0] = (float)cls0;               o4[p1] = (float)cls1; }

    // one-hot * mask: dq lanes split the 21 columns (6+6+6+3)
    #pragma unroll
    for (int j = 0; j < 6; ++j) {
        const int c = dq * 6 + j;
        if (c < NCAT) {
            o0[p0 * NCAT + c] = (m0 && c == cls0) ? 1.0f : 0.0f;
            o0[p1 * NCAT + c] = (m1 && c == cls1) ? 1.0f : 0.0f;
        }
    }
}

extern "C" void kernel_launch(void* const* d_in, const int* in_sizes, int n_in,
                              void* d_out, int out_size, void* d_ws, size_t ws_size,
                              hipStream_t stream) {
    const float* frame = (const float*)d_in[0];
    const float* tmpl  = (const float*)d_in[1];
    const int*   tcls  = (const int*)d_in[2];
    float* outp = (float*)d_out;
    nn_openset_kernel<<<NPIX / P, 256, 0, stream>>>(frame, tmpl, tcls, outp);
}